// Round 17
// baseline (207.338 us; speedup 1.0000x reference)
//
#include <hip/hip_runtime.h>
#include <stdint.h>

#define BB 32
#define CC 256
#define HH 56
#define WW 56
#define TAPS 9
#define NCONV 3
#define BN_EPS 1e-5f

typedef int   int4v __attribute__((ext_vector_type(4)));
typedef float f16v  __attribute__((ext_vector_type(16)));

// f8f6f4 MFMA, cbsz=4/blgp=4 -> FP4 A/B, 4-reg tuples, tied in-place acc
// (r14/r16-verified: exact sign-dot, no spill).
#define MFMA_FP4(accv, av, bv) \
    asm("v_mfma_f32_32x32x64_f8f6f4 %0, %1, %2, %0 cbsz:4 blgp:4" \
        : "+v"(accv) : "v"(av), "v"(bv))

// ---------------- workspace layout (bytes) ----------------
// act4 : [n][56][56][128]  fp4 nibbles, ch-last   (verified)
// wpk4 : [((j*8+ot)*4+g)*9+t][ln64][16]           (verified)
#define ACT4_BYTES ((size_t)BB * HH * WW * 128)
#define WPK4_BYTES ((size_t)NCONV * 8 * 4 * TAPS * 64 * 16)
#define OT4_STRIDE 36864                 // (+1 ot) * 4 g * 9 t * 1024

// LDS: per-phase tile = 2 groups x [4 rows][58 cols][32 B], XOR swizzle.
#define L_PX   32
#define L_ROW  (58 * L_PX)               // 1856
#define L_G    (4 * L_ROW)               // 7424 per group
#define L_P2   (2 * L_G)                 // 14848 per buffer (2 groups)
#define NST2   928                       // 16B staging units per 2-group tile
#define SWZ(c) ((((c) ^ ((c) >> 2)) & 3) << 4)

// act4[n][h][w][byte]: byte = fp4(ch 2b) | fp4(ch 2b+1)<<4 (verified).
__global__ __launch_bounds__(256) void pack_act4_kernel(
    const float* __restrict__ x, const float* __restrict__ bias0,
    uint8_t* __restrict__ act4)
{
    __shared__ uint8_t nib[56 * 260];
    const int tid = threadIdx.x;
    const int h = blockIdx.x % HH, n = blockIdx.x / HH;
    const int w = tid & 63;
    const int cq = tid >> 6;
    if (w < WW) {
        #pragma unroll 4
        for (int cc = 0; cc < 64; ++cc) {
            const int c = cc * 4 + cq;
            const float v = x[((size_t)(n * CC + c) * HH + h) * WW + w] + bias0[c];
            nib[w * 260 + c] = (v > 0.f) ? 0x2 : ((v < 0.f) ? 0xA : 0x0);
        }
    }
    __syncthreads();
    uint32_t* o32 = (uint32_t*)(act4 + (size_t)(n * HH + h) * WW * 128);
    #pragma unroll
    for (int i = 0; i < 7; ++i) {
        const int flat = i * 1024 + tid * 4;
        const int ww = flat >> 7, b0 = flat & 127;
        uint32_t r = 0;
        #pragma unroll
        for (int k = 0; k < 4; ++k) {
            const int b = b0 + k;
            const uint32_t lo = nib[ww * 260 + 2 * b];
            const uint32_t hi = nib[ww * 260 + 2 * b + 1];
            r |= ((lo | (hi << 4)) & 0xFFu) << (8 * k);
        }
        o32[flat >> 2] = r;
    }
}

// per-o scale = mean |w| ; epack fused (one wave per (j,o)).
__global__ __launch_bounds__(64) void pack_scales_kernel(
    const float* __restrict__ w0, const float* __restrict__ w1,
    const float* __restrict__ w2, float* __restrict__ scales,
    const float* __restrict__ gamma, const float* __restrict__ beta,
    const float* __restrict__ rmean, const float* __restrict__ rvar,
    const float* __restrict__ bias1, const float* __restrict__ prelu_a,
    const float* __restrict__ bias2, float* __restrict__ epack)
{
    const int j = blockIdx.x >> 8;
    const int o = blockIdx.x & 255;
    const float* wp = (j == 0) ? w0 : ((j == 1) ? w1 : w2);
    const int lane = threadIdx.x;
    const float* wo = wp + (size_t)o * CC * TAPS;
    float s = 0.f;
    for (int k = lane; k < CC * TAPS; k += 64) s += fabsf(wo[k]);
    #pragma unroll
    for (int d = 32; d > 0; d >>= 1) s += __shfl_xor(s, d);
    if (lane == 0) scales[j * CC + o] = s * (1.0f / (float)(CC * TAPS));
    if (j == 0 && lane == 0) {
        const float A = gamma[o] * rsqrtf(rvar[o] + BN_EPS);
        epack[o * 4 + 0] = A;
        epack[o * 4 + 1] = beta[o] - rmean[o] * A + bias1[o];
        epack[o * 4 + 2] = prelu_a[o];
        epack[o * 4 + 3] = bias2[o];
    }
}

// weight fp4 nibbles in A-fragment order (verified).
__global__ __launch_bounds__(256) void pack_wpk4_kernel(
    const float* __restrict__ w0, const float* __restrict__ w1,
    const float* __restrict__ w2, uint8_t* __restrict__ wpk)
{
    const int j  = blockIdx.x >> 3;
    const int ot = blockIdx.x & 7;
    const float* wp = (j == 0) ? w0 : ((j == 1) ? w1 : w2);
    #pragma unroll 1
    for (int it = 0; it < 9; ++it) {
        const int e = it * 256 + threadIdx.x;     // 0..2303
        const int g = e / 576;
        const int rem = e % 576;
        const int t = rem >> 6;
        const int ln = rem & 63;
        const int o = ot * 32 + (ln & 31);
        const int chb = g * 64 + ((ln >> 5) & 1) * 32;
        uint8_t bytes[16];
        #pragma unroll
        for (int b = 0; b < 16; ++b) {
            const float vlo = wp[((size_t)o * CC + chb + 2 * b) * TAPS + t];
            const float vhi = wp[((size_t)o * CC + chb + 2 * b + 1) * TAPS + t];
            const uint8_t nlo = (vlo > 0.f) ? 0x2 : ((vlo < 0.f) ? 0xA : 0x0);
            const uint8_t nhi = (vhi > 0.f) ? 0x2 : ((vhi < 0.f) ? 0xA : 0x0);
            bytes[b] = (uint8_t)(nlo | (nhi << 4));
        }
        *(int4v*)(wpk + ((size_t)((j * 8 + ot) * 4 + g) * 9 + t) * 1024 + ln * 16)
            = *(const int4v*)bytes;
    }
}

// main: fp4 MFMA conv, r16 structure with register diet for 3 waves/SIMD:
// A/B rings depth 2, sreg[2] with two-half staging. 6 phases x 72 MFMA.
__global__ __launch_bounds__(256) void conv_mfma4_kernel(
    const uint8_t* __restrict__ act4, const uint8_t* __restrict__ wpk,
    const float* __restrict__ scales, const float* __restrict__ epack,
    const float* __restrict__ x, float* __restrict__ out)
{
    __shared__ __align__(16) uint8_t lds[2][L_P2];
    const int tid  = threadIdx.x;
    const int lane = tid & 63;
    const int wv   = __builtin_amdgcn_readfirstlane(tid >> 6);
    const int bid  = blockIdx.x;
    const int swz  = (bid & 7) * 196 + (bid >> 3);   // bijective: 1568 = 8*196
    const int pxblk = swz % 49;
    const int n     = swz / 49;
    const int px0   = pxblk * 64;
    const int h_lo  = px0 / WW;

    // per-lane swizzled LDS bases: [px tile][tap col] (verified formula)
    int boff[2][3];
    #pragma unroll
    for (int pt = 0; pt < 2; ++pt) {
        const int p = px0 + pt * 32 + (lane & 31);
        const int hl = p / WW, wl = p % WW;
        #pragma unroll
        for (int tc = 0; tc < 3; ++tc) {
            const int col = wl + tc;
            const int a = (hl - h_lo) * L_ROW + col * L_PX + ((lane >> 5) & 1) * 16;
            boff[pt][tc] = a ^ SWZ(col);
        }
    }
    const size_t nbase = (size_t)n * HH;

    float fsum[2][2][16];
    #pragma unroll
    for (int q = 0; q < 2; ++q)
        #pragma unroll
        for (int pt = 0; pt < 2; ++pt)
            #pragma unroll
            for (int r = 0; r < 16; ++r) fsum[q][pt][r] = 0.f;

    f16v acc[2][2];
    int4v sreg[2];
    int4v Ar[2][2], Br[2][2];

    // staging in halves: half*512 + k*256 covers units 0..511 / 512..927
    auto stage_load = [&](int jj, int gp, int half) {
        const int amt = (jj == 0) ? 0 : ((jj == 1) ? 1 : 3);
        #pragma unroll
        for (int k = 0; k < 2; ++k) {
            const int u = tid + half * 512 + k * 256;
            int4v v = {0, 0, 0, 0};
            if (u < NST2) {
                const int gl = u / 464;
                const int vv = u - gl * 464;
                const int r = vv / 116;
                const int rem = vv - r * 116;
                const int c = rem >> 1, q = rem & 1;
                const int g = gp * 2 + gl;
                const int rH = (g == 0) ? -amt : ((g == 1) ? amt : 0);
                const int rW = (g == 2) ? -amt : ((g == 3) ? amt : 0);
                const int hr = h_lo - 1 + r, wc = c - 1;
                if (hr >= 0 && hr < HH && wc >= 0 && wc < WW) {
                    int hs = hr + rH; if (hs < 0) hs += HH; else if (hs >= HH) hs -= HH;
                    int ws = wc + rW; if (ws < 0) ws += WW; else if (ws >= WW) ws -= WW;
                    v = *(const int4v*)(act4 +
                        (((nbase + hs) * WW + ws) << 7) + g * 32 + q * 16);
                }
            }
            sreg[k] = v;
        }
    };
    auto stage_write = [&](uint8_t* Ln, int half) {
        #pragma unroll
        for (int k = 0; k < 2; ++k) {
            const int u = tid + half * 512 + k * 256;
            if (u < NST2) {
                const int gl = u / 464;
                const int vv = u - gl * 464;
                const int r = vv / 116;
                const int rem = vv - r * 116;
                const int c = rem >> 1, q = rem & 1;
                int a = gl * L_G + r * L_ROW + c * L_PX + q * 16;
                a ^= SWZ(c);
                *(int4v*)(Ln + a) = sreg[k];
            }
        }
    };

#define LDA4(S, U) do { \
        Ar[S][0] = *(const int4v*)(wbase + (U) * 1024); \
        Ar[S][1] = *(const int4v*)(wbase + OT4_STRIDE + (U) * 1024); } while (0)
#define LDB4(S, U) do { \
        const int gl_ = (U) / 9, t_ = (U) % 9; \
        const int imm_ = gl_ * L_G + (t_ / 3) * L_ROW; \
        const int tc_ = t_ % 3; \
        Br[S][0] = *(const int4v*)(L + boff[0][tc_] + imm_); \
        Br[S][1] = *(const int4v*)(L + boff[1][tc_] + imm_); } while (0)
#define MMX4(S) do { \
        MFMA_FP4(acc[0][0], Ar[S][0], Br[S][0]); \
        MFMA_FP4(acc[0][1], Ar[S][0], Br[S][1]); \
        MFMA_FP4(acc[1][0], Ar[S][1], Br[S][0]); \
        MFMA_FP4(acc[1][1], Ar[S][1], Br[S][1]); } while (0)

    // ---- prologue: stage phase 0 (both halves); preload A units 0..1 ----
    stage_load(0, 0, 0);
    stage_write(&lds[0][0], 0);
    stage_load(0, 0, 1);
    stage_write(&lds[0][0], 1);
    {
        const uint8_t* wbase = wpk
            + ((size_t)((0 * 8 + wv * 2) * 4 + 0) * 9) * 1024 + lane * 16;
        LDA4(0, 0); LDA4(1, 1);
    }
    __syncthreads();

    #pragma unroll 1
    for (int ph = 0; ph < 6; ++ph) {
        const int j = ph >> 1, gp = ph & 1;
        if (gp == 0) {
            #pragma unroll
            for (int q = 0; q < 2; ++q)
                #pragma unroll
                for (int pt = 0; pt < 2; ++pt) acc[q][pt] = (f16v)0.f;
        }

        const uint8_t* L = &lds[ph & 1][0];
        const uint8_t* wbase = wpk
            + ((size_t)((j * 8 + wv * 2) * 4 + gp * 2) * 9) * 1024 + lane * 16;

        // B prologue (buffer valid post-barrier)
        LDB4(0, 0); LDB4(1, 1);

        // prefetch next phase act tiles, first half
        const int ph2 = ph + 1;
        if (ph < 5) stage_load(ph2 >> 1, ph2 & 1, 0);

        __builtin_amdgcn_s_setprio(1);
        MMX4(0); LDA4(0, 2);  LDB4(0, 2);
        MMX4(1); LDA4(1, 3);  LDB4(1, 3);
        MMX4(0); LDA4(0, 4);  LDB4(0, 4);
        MMX4(1); LDA4(1, 5);  LDB4(1, 5);
        MMX4(0); LDA4(0, 6);  LDB4(0, 6);
        MMX4(1); LDA4(1, 7);  LDB4(1, 7);
        MMX4(0); LDA4(0, 8);  LDB4(0, 8);
        MMX4(1); LDA4(1, 9);  LDB4(1, 9);
        MMX4(0); LDA4(0, 10); LDB4(0, 10);
        MMX4(1); LDA4(1, 11); LDB4(1, 11);
        MMX4(0); LDA4(0, 12); LDB4(0, 12);
        MMX4(1); LDA4(1, 13); LDB4(1, 13);
        MMX4(0); LDA4(0, 14); LDB4(0, 14);
        MMX4(1); LDA4(1, 15); LDB4(1, 15);
        MMX4(0); LDA4(0, 16); LDB4(0, 16);
        MMX4(1); LDA4(1, 17); LDB4(1, 17);
        MMX4(0);
        MMX4(1);
        __builtin_amdgcn_s_setprio(0);

        if (ph < 5) {
            // write half 0, then load+write half 1 (post-burst, cheap slot)
            uint8_t* Ln = &lds[(ph + 1) & 1][0];
            stage_write(Ln, 0);
            stage_load(ph2 >> 1, ph2 & 1, 1);
            // hoisted A prologue for next phase (overlaps half-1 load latency)
            const int j2 = ph2 >> 1, gp2 = ph2 & 1;
            const uint8_t* wbase2 = wpk
                + ((size_t)((j2 * 8 + wv * 2) * 4 + gp2 * 2) * 9) * 1024 + lane * 16;
            Ar[0][0] = *(const int4v*)(wbase2);
            Ar[0][1] = *(const int4v*)(wbase2 + OT4_STRIDE);
            Ar[1][0] = *(const int4v*)(wbase2 + 1024);
            Ar[1][1] = *(const int4v*)(wbase2 + OT4_STRIDE + 1024);
            stage_write(Ln, 1);
        }

        // fold at end of each j (acc f32, exact integers)
        if (gp == 1) {
            const float* scj = scales + j * CC + wv * 64;
            #pragma unroll
            for (int q = 0; q < 2; ++q) {
                #pragma unroll
                for (int r = 0; r < 16; ++r) {
                    const int rb = q * 32 + (r & 3) + 8 * (r >> 2);
                    const float slo = scj[rb], shi = scj[rb + 4];
                    const float sc = (lane & 32) ? shi : slo;
                    fsum[q][0][r] += sc * acc[q][0][r];
                    fsum[q][1][r] += sc * acc[q][1][r];
                }
            }
        }
        __syncthreads();
    }
#undef LDA4
#undef LDB4
#undef MMX4

    // epilogue (D layout: col=lane&31 -> px, row=(r&3)+8*(r>>2)+4*(lane>>5))
    const int voff = (lane & 31) + ((lane >> 5) & 1) * (4 * HH * WW);
    #pragma unroll
    for (int q = 0; q < 2; ++q) {
        #pragma unroll
        for (int r = 0; r < 16; ++r) {
            const int o_lo = wv * 64 + q * 32 + (r & 3) + 8 * (r >> 2);
            const float* elo = epack + o_lo * 4;
            const float* ehi = epack + (o_lo + 4) * 4;
            const bool hi = (lane & 32) != 0;
            const float e0 = hi ? ehi[0] : elo[0];
            const float e1 = hi ? ehi[1] : elo[1];
            const float e2 = hi ? ehi[2] : elo[2];
            const float e3 = hi ? ehi[3] : elo[3];
            const size_t base = ((size_t)n * CC + o_lo) * (HH * WW) + px0;
            #pragma unroll
            for (int pt = 0; pt < 2; ++pt) {
                const size_t off = base + pt * 32 + voff;
                float v = fsum[q][pt][r] * e0 + e1 + x[off];
                v = (v > 0.f) ? v : e2 * v;
                out[off] = v + e3;
            }
        }
    }
}

// ===========================================================================
extern "C" void kernel_launch(void* const* d_in, const int* in_sizes, int n_in,
                              void* d_out, int out_size, void* d_ws, size_t ws_size,
                              hipStream_t stream) {
    const float* x       = (const float*)d_in[0];
    const float* bias0   = (const float*)d_in[1];
    const float* w0      = (const float*)d_in[2];
    const float* w1      = (const float*)d_in[3];
    const float* w2      = (const float*)d_in[4];
    const float* gamma   = (const float*)d_in[5];
    const float* beta    = (const float*)d_in[6];
    const float* rmean   = (const float*)d_in[7];
    const float* rvar    = (const float*)d_in[8];
    const float* bias1   = (const float*)d_in[9];
    const float* prelu_a = (const float*)d_in[10];
    const float* bias2   = (const float*)d_in[11];
    float* out = (float*)d_out;

    uint8_t* act4   = (uint8_t*)d_ws;
    uint8_t* wpk    = act4 + ACT4_BYTES;
    float*   scales = (float*)(wpk + WPK4_BYTES);
    float*   epack  = scales + NCONV * CC;

    pack_act4_kernel<<<dim3(BB * HH), dim3(256), 0, stream>>>(x, bias0, act4);
    pack_scales_kernel<<<dim3(NCONV * CC), dim3(64), 0, stream>>>(
        w0, w1, w2, scales, gamma, beta, rmean, rvar, bias1, prelu_a, bias2, epack);
    pack_wpk4_kernel<<<dim3(NCONV * 8), dim3(256), 0, stream>>>(w0, w1, w2, wpk);
    conv_mfma4_kernel<<<dim3(BB * 49), dim3(256), 0, stream>>>(
        act4, wpk, scales, epack, x, out);
}

// Round 18
// 177.906 us; speedup vs baseline: 1.1654x; 1.1654x over previous
//
#include <hip/hip_runtime.h>
#include <stdint.h>

#define BB 32
#define CC 256
#define HH 56
#define WW 56
#define TAPS 9
#define NCONV 3
#define BN_EPS 1e-5f

typedef int   int4v __attribute__((ext_vector_type(4)));
typedef float f16v  __attribute__((ext_vector_type(16)));

// f8f6f4 MFMA, cbsz=4/blgp=4 -> FP4 A/B, 4-reg tuples, tied in-place acc
// (r14/r16-verified: exact sign-dot, no spill).
#define MFMA_FP4(accv, av, bv) \
    asm("v_mfma_f32_32x32x64_f8f6f4 %0, %1, %2, %0 cbsz:4 blgp:4" \
        : "+v"(accv) : "v"(av), "v"(bv))

// ---------------- workspace layout (bytes) ----------------
// act4 : [n][56][56][128]  fp4 nibbles, ch-last   (verified)
// wpk4 : [((j*8+ot)*4+g)*9+t][ln64][16]           (verified)
#define ACT4_BYTES ((size_t)BB * HH * WW * 128)
#define WPK4_BYTES ((size_t)NCONV * 8 * 4 * TAPS * 64 * 16)
#define OT4_STRIDE 36864                 // (+1 ot) * 4 g * 9 t * 1024

// LDS: per-phase tile = 2 groups x [4 rows][58 cols][32 B], XOR swizzle.
#define L_PX   32
#define L_ROW  (58 * L_PX)               // 1856
#define L_G    (4 * L_ROW)               // 7424 per group
#define L_P2   (2 * L_G)                 // 14848 per buffer (2 groups)
#define NST2   928                       // 16B staging units per 2-group tile
#define SWZ(c) ((((c) ^ ((c) >> 2)) & 3) << 4)

// act4[n][h][w][byte]: byte = fp4(ch 2b) | fp4(ch 2b+1)<<4 (verified).
__global__ __launch_bounds__(256) void pack_act4_kernel(
    const float* __restrict__ x, const float* __restrict__ bias0,
    uint8_t* __restrict__ act4)
{
    __shared__ uint8_t nib[56 * 260];
    const int tid = threadIdx.x;
    const int h = blockIdx.x % HH, n = blockIdx.x / HH;
    const int w = tid & 63;
    const int cq = tid >> 6;
    if (w < WW) {
        #pragma unroll 4
        for (int cc = 0; cc < 64; ++cc) {
            const int c = cc * 4 + cq;
            const float v = x[((size_t)(n * CC + c) * HH + h) * WW + w] + bias0[c];
            nib[w * 260 + c] = (v > 0.f) ? 0x2 : ((v < 0.f) ? 0xA : 0x0);
        }
    }
    __syncthreads();
    uint32_t* o32 = (uint32_t*)(act4 + (size_t)(n * HH + h) * WW * 128);
    #pragma unroll
    for (int i = 0; i < 7; ++i) {
        const int flat = i * 1024 + tid * 4;
        const int ww = flat >> 7, b0 = flat & 127;
        uint32_t r = 0;
        #pragma unroll
        for (int k = 0; k < 4; ++k) {
            const int b = b0 + k;
            const uint32_t lo = nib[ww * 260 + 2 * b];
            const uint32_t hi = nib[ww * 260 + 2 * b + 1];
            r |= ((lo | (hi << 4)) & 0xFFu) << (8 * k);
        }
        o32[flat >> 2] = r;
    }
}

// merged weight prep: blocks 0..23 pack wpk4 fragments (verbatim r16 logic);
// blocks 24..215 compute scales (4 (j,o) pairs per block, wave each) + epack.
__global__ __launch_bounds__(256) void pack_wprep_kernel(
    const float* __restrict__ w0, const float* __restrict__ w1,
    const float* __restrict__ w2, uint8_t* __restrict__ wpk,
    float* __restrict__ scales,
    const float* __restrict__ gamma, const float* __restrict__ beta,
    const float* __restrict__ rmean, const float* __restrict__ rvar,
    const float* __restrict__ bias1, const float* __restrict__ prelu_a,
    const float* __restrict__ bias2, float* __restrict__ epack)
{
    const int bid = blockIdx.x;
    if (bid < 24) {
        // ---- wpk4 packing (verified r16 logic, verbatim) ----
        const int j  = bid >> 3;
        const int ot = bid & 7;
        const float* wp = (j == 0) ? w0 : ((j == 1) ? w1 : w2);
        #pragma unroll 1
        for (int it = 0; it < 9; ++it) {
            const int e = it * 256 + threadIdx.x;     // 0..2303
            const int g = e / 576;
            const int rem = e % 576;
            const int t = rem >> 6;
            const int ln = rem & 63;
            const int o = ot * 32 + (ln & 31);
            const int chb = g * 64 + ((ln >> 5) & 1) * 32;
            uint8_t bytes[16];
            #pragma unroll
            for (int b = 0; b < 16; ++b) {
                const float vlo = wp[((size_t)o * CC + chb + 2 * b) * TAPS + t];
                const float vhi = wp[((size_t)o * CC + chb + 2 * b + 1) * TAPS + t];
                const uint8_t nlo = (vlo > 0.f) ? 0x2 : ((vlo < 0.f) ? 0xA : 0x0);
                const uint8_t nhi = (vhi > 0.f) ? 0x2 : ((vhi < 0.f) ? 0xA : 0x0);
                bytes[b] = (uint8_t)(nlo | (nhi << 4));
            }
            *(int4v*)(wpk + ((size_t)((j * 8 + ot) * 4 + g) * 9 + t) * 1024 + ln * 16)
                = *(const int4v*)bytes;
        }
    } else {
        // ---- scales + epack (verified r16 logic; 4 (j,o) pairs per block) ----
        const int pair = (bid - 24) * 4 + (threadIdx.x >> 6);   // 0..767
        const int j = pair >> 8;
        const int o = pair & 255;
        const float* wp = (j == 0) ? w0 : ((j == 1) ? w1 : w2);
        const int lane = threadIdx.x & 63;
        const float* wo = wp + (size_t)o * CC * TAPS;
        float s = 0.f;
        for (int k = lane; k < CC * TAPS; k += 64) s += fabsf(wo[k]);
        #pragma unroll
        for (int d = 32; d > 0; d >>= 1) s += __shfl_xor(s, d);
        if (lane == 0) scales[j * CC + o] = s * (1.0f / (float)(CC * TAPS));
        if (j == 0 && lane == 0) {
            const float A = gamma[o] * rsqrtf(rvar[o] + BN_EPS);
            epack[o * 4 + 0] = A;
            epack[o * 4 + 1] = beta[o] - rmean[o] * A + bias1[o];
            epack[o * 4 + 2] = prelu_a[o];
            epack[o * 4 + 3] = bias2[o];
        }
    }
}

// main: fp4 MFMA conv (r16-verified champion, byte-identical).
// 256 thr, 4 waves (O=2 ot-pair x P=2 px-tiles); 6 phases x 72-MFMA bursts;
// dbuf LDS 2x14.8KB; A/B rings depth 3; hoisted A prologue.
__global__ __launch_bounds__(256) void conv_mfma4_kernel(
    const uint8_t* __restrict__ act4, const uint8_t* __restrict__ wpk,
    const float* __restrict__ scales, const float* __restrict__ epack,
    const float* __restrict__ x, float* __restrict__ out)
{
    __shared__ __align__(16) uint8_t lds[2][L_P2];
    const int tid  = threadIdx.x;
    const int lane = tid & 63;
    const int wv   = __builtin_amdgcn_readfirstlane(tid >> 6);
    const int bid  = blockIdx.x;
    const int swz  = (bid & 7) * 196 + (bid >> 3);   // bijective: 1568 = 8*196
    const int pxblk = swz % 49;
    const int n     = swz / 49;
    const int px0   = pxblk * 64;
    const int h_lo  = px0 / WW;

    // per-lane swizzled LDS bases: [px tile][tap col] (verified formula)
    int boff[2][3];
    #pragma unroll
    for (int pt = 0; pt < 2; ++pt) {
        const int p = px0 + pt * 32 + (lane & 31);
        const int hl = p / WW, wl = p % WW;
        #pragma unroll
        for (int tc = 0; tc < 3; ++tc) {
            const int col = wl + tc;
            const int a = (hl - h_lo) * L_ROW + col * L_PX + ((lane >> 5) & 1) * 16;
            boff[pt][tc] = a ^ SWZ(col);
        }
    }
    const size_t nbase = (size_t)n * HH;

    float fsum[2][2][16];
    #pragma unroll
    for (int q = 0; q < 2; ++q)
        #pragma unroll
        for (int pt = 0; pt < 2; ++pt)
            #pragma unroll
            for (int r = 0; r < 16; ++r) fsum[q][pt][r] = 0.f;

    f16v acc[2][2];
    int4v sreg[4];
    int4v Ar[3][2], Br[3][2];

    // staging: 2 groups x 464 units per phase (verified formulas)
    auto stage_load = [&](int jj, int gp) {
        const int amt = (jj == 0) ? 0 : ((jj == 1) ? 1 : 3);
        #pragma unroll
        for (int k = 0; k < 4; ++k) {
            const int u = tid + k * 256;
            int4v v = {0, 0, 0, 0};
            if (u < NST2) {
                const int gl = u / 464;
                const int vv = u - gl * 464;
                const int r = vv / 116;
                const int rem = vv - r * 116;
                const int c = rem >> 1, q = rem & 1;
                const int g = gp * 2 + gl;
                const int rH = (g == 0) ? -amt : ((g == 1) ? amt : 0);
                const int rW = (g == 2) ? -amt : ((g == 3) ? amt : 0);
                const int hr = h_lo - 1 + r, wc = c - 1;
                if (hr >= 0 && hr < HH && wc >= 0 && wc < WW) {
                    int hs = hr + rH; if (hs < 0) hs += HH; else if (hs >= HH) hs -= HH;
                    int ws = wc + rW; if (ws < 0) ws += WW; else if (ws >= WW) ws -= WW;
                    v = *(const int4v*)(act4 +
                        (((nbase + hs) * WW + ws) << 7) + g * 32 + q * 16);
                }
            }
            sreg[k] = v;
        }
    };
    auto stage_write = [&](uint8_t* Ln) {
        #pragma unroll
        for (int k = 0; k < 4; ++k) {
            const int u = tid + k * 256;
            if (u < NST2) {
                const int gl = u / 464;
                const int vv = u - gl * 464;
                const int r = vv / 116;
                const int rem = vv - r * 116;
                const int c = rem >> 1, q = rem & 1;
                int a = gl * L_G + r * L_ROW + c * L_PX + q * 16;
                a ^= SWZ(c);
                *(int4v*)(Ln + a) = sreg[k];
            }
        }
    };

#define LDA4(S, U) do { \
        Ar[S][0] = *(const int4v*)(wbase + (U) * 1024); \
        Ar[S][1] = *(const int4v*)(wbase + OT4_STRIDE + (U) * 1024); } while (0)
#define LDB4(S, U) do { \
        const int gl_ = (U) / 9, t_ = (U) % 9; \
        const int imm_ = gl_ * L_G + (t_ / 3) * L_ROW; \
        const int tc_ = t_ % 3; \
        Br[S][0] = *(const int4v*)(L + boff[0][tc_] + imm_); \
        Br[S][1] = *(const int4v*)(L + boff[1][tc_] + imm_); } while (0)
#define MMX4(S) do { \
        MFMA_FP4(acc[0][0], Ar[S][0], Br[S][0]); \
        MFMA_FP4(acc[0][1], Ar[S][0], Br[S][1]); \
        MFMA_FP4(acc[1][0], Ar[S][1], Br[S][0]); \
        MFMA_FP4(acc[1][1], Ar[S][1], Br[S][1]); } while (0)

    // ---- prologue: stage phase 0 (j=0, groups 0-1); preload A units 0..2 ----
    stage_load(0, 0);
    stage_write(&lds[0][0]);
    {
        const uint8_t* wbase = wpk
            + ((size_t)((0 * 8 + wv * 2) * 4 + 0) * 9) * 1024 + lane * 16;
        LDA4(0, 0); LDA4(1, 1); LDA4(2, 2);
    }
    __syncthreads();

    #pragma unroll 1
    for (int ph = 0; ph < 6; ++ph) {
        const int j = ph >> 1, gp = ph & 1;
        if (gp == 0) {
            #pragma unroll
            for (int q = 0; q < 2; ++q)
                #pragma unroll
                for (int pt = 0; pt < 2; ++pt) acc[q][pt] = (f16v)0.f;
        }

        const uint8_t* L = &lds[ph & 1][0];
        const uint8_t* wbase = wpk
            + ((size_t)((j * 8 + wv * 2) * 4 + gp * 2) * 9) * 1024 + lane * 16;

        // B prologue (buffer valid post-barrier)
        LDB4(0, 0); LDB4(1, 1); LDB4(2, 2);

        // prefetch next phase act tiles into regs
        if (ph < 5) {
            const int ph2 = ph + 1;
            stage_load(ph2 >> 1, ph2 & 1);
        }

        __builtin_amdgcn_s_setprio(1);
        MMX4(0); LDA4(0, 3);  LDB4(0, 3);
        MMX4(1); LDA4(1, 4);  LDB4(1, 4);
        MMX4(2); LDA4(2, 5);  LDB4(2, 5);
        MMX4(0); LDA4(0, 6);  LDB4(0, 6);
        MMX4(1); LDA4(1, 7);  LDB4(1, 7);
        MMX4(2); LDA4(2, 8);  LDB4(2, 8);
        MMX4(0); LDA4(0, 9);  LDB4(0, 9);
        MMX4(1); LDA4(1, 10); LDB4(1, 10);
        MMX4(2); LDA4(2, 11); LDB4(2, 11);
        MMX4(0); LDA4(0, 12); LDB4(0, 12);
        MMX4(1); LDA4(1, 13); LDB4(1, 13);
        MMX4(2); LDA4(2, 14); LDB4(2, 14);
        MMX4(0); LDA4(0, 15); LDB4(0, 15);
        MMX4(1); LDA4(1, 16); LDB4(1, 16);
        MMX4(2); LDA4(2, 17); LDB4(2, 17);
        MMX4(0);
        MMX4(1);
        MMX4(2);
        __builtin_amdgcn_s_setprio(0);

        // hoisted A prologue for next phase (no LDS dependency)
        if (ph < 5) {
            const int ph2 = ph + 1;
            const int j2 = ph2 >> 1, gp2 = ph2 & 1;
            const uint8_t* wbase = wpk
                + ((size_t)((j2 * 8 + wv * 2) * 4 + gp2 * 2) * 9) * 1024 + lane * 16;
            LDA4(0, 0); LDA4(1, 1); LDA4(2, 2);
        }

        // write next act tiles into the other buffer
        if (ph < 5) stage_write(&lds[(ph + 1) & 1][0]);

        // fold at end of each j (acc f32, exact integers)
        if (gp == 1) {
            const float* scj = scales + j * CC + wv * 64;
            #pragma unroll
            for (int q = 0; q < 2; ++q) {
                #pragma unroll
                for (int r = 0; r < 16; ++r) {
                    const int rb = q * 32 + (r & 3) + 8 * (r >> 2);
                    const float slo = scj[rb], shi = scj[rb + 4];
                    const float sc = (lane & 32) ? shi : slo;
                    fsum[q][0][r] += sc * acc[q][0][r];
                    fsum[q][1][r] += sc * acc[q][1][r];
                }
            }
        }
        __syncthreads();
    }
#undef LDA4
#undef LDB4
#undef MMX4

    // epilogue (D layout: col=lane&31 -> px, row=(r&3)+8*(r>>2)+4*(lane>>5))
    const int voff = (lane & 31) + ((lane >> 5) & 1) * (4 * HH * WW);
    #pragma unroll
    for (int q = 0; q < 2; ++q) {
        #pragma unroll
        for (int r = 0; r < 16; ++r) {
            const int o_lo = wv * 64 + q * 32 + (r & 3) + 8 * (r >> 2);
            const float* elo = epack + o_lo * 4;
            const float* ehi = epack + (o_lo + 4) * 4;
            const bool hi = (lane & 32) != 0;
            const float e0 = hi ? ehi[0] : elo[0];
            const float e1 = hi ? ehi[1] : elo[1];
            const float e2 = hi ? ehi[2] : elo[2];
            const float e3 = hi ? ehi[3] : elo[3];
            const size_t base = ((size_t)n * CC + o_lo) * (HH * WW) + px0;
            #pragma unroll
            for (int pt = 0; pt < 2; ++pt) {
                const size_t off = base + pt * 32 + voff;
                float v = fsum[q][pt][r] * e0 + e1 + x[off];
                v = (v > 0.f) ? v : e2 * v;
                out[off] = v + e3;
            }
        }
    }
}

// ===========================================================================
extern "C" void kernel_launch(void* const* d_in, const int* in_sizes, int n_in,
                              void* d_out, int out_size, void* d_ws, size_t ws_size,
                              hipStream_t stream) {
    const float* x       = (const float*)d_in[0];
    const float* bias0   = (const float*)d_in[1];
    const float* w0      = (const float*)d_in[2];
    const float* w1      = (const float*)d_in[3];
    const float* w2      = (const float*)d_in[4];
    const float* gamma   = (const float*)d_in[5];
    const float* beta    = (const float*)d_in[6];
    const float* rmean   = (const float*)d_in[7];
    const float* rvar    = (const float*)d_in[8];
    const float* bias1   = (const float*)d_in[9];
    const float* prelu_a = (const float*)d_in[10];
    const float* bias2   = (const float*)d_in[11];
    float* out = (float*)d_out;

    uint8_t* act4   = (uint8_t*)d_ws;
    uint8_t* wpk    = act4 + ACT4_BYTES;
    float*   scales = (float*)(wpk + WPK4_BYTES);
    float*   epack  = scales + NCONV * CC;

    pack_act4_kernel<<<dim3(BB * HH), dim3(256), 0, stream>>>(x, bias0, act4);
    pack_wprep_kernel<<<dim3(216), dim3(256), 0, stream>>>(
        w0, w1, w2, wpk, scales,
        gamma, beta, rmean, rvar, bias1, prelu_a, bias2, epack);
    conv_mfma4_kernel<<<dim3(BB * 49), dim3(256), 0, stream>>>(
        act4, wpk, scales, epack, x, out);
}